// Round 4
// baseline (6501.398 us; speedup 1.0000x reference)
//
#include <hip/hip_runtime.h>
#include <hip/hip_bf16.h>
#include <math.h>

// ---- problem constants -------------------------------------------------
#define L_    7
#define H_    8
#define DF_   980
#define DP_   44
#define DD_   1024
#define HDIM  128
#define FF_   4096
#define B_    16
#define NSEQ  256
#define MTOK  4096          // B_*NSEQ
#define HID_  512
#define NFREQ 5997
#define KP0   12032         // 2*NFREQ=11994 padded to mult of 64

typedef __attribute__((ext_vector_type(8))) short short8_t;
typedef __attribute__((ext_vector_type(4))) float f32x4;

// ---- bf16 split helpers ------------------------------------------------
__device__ __forceinline__ unsigned short bf16_hi(float v) {
    __hip_bfloat16 b = __float2bfloat16(v);
    union { __hip_bfloat16 b; unsigned short u; } c; c.b = b; return c.u;
}
__device__ __forceinline__ float bf16_to_f(unsigned short u) {
    union { unsigned int x; float f; } c; c.x = ((unsigned int)u) << 16; return c.f;
}
__device__ __forceinline__ void bf16_split(float v, unsigned short& h, unsigned short& l) {
    h = bf16_hi(v);
    l = bf16_hi(v - bf16_to_f(h));
}

// async global->LDS, 16B per lane (wave-uniform LDS base + lane*16)
__device__ __forceinline__ void gl_lds16(const void* g, void* l) {
    __builtin_amdgcn_global_load_lds(
        (const __attribute__((address_space(1))) void*)g,
        (__attribute__((address_space(3))) void*)l, 16, 0, 0);
}

// ======================================================================
// Fourier features -> bf16 hi plane h0h [4096][KP0], zero-padded cols.
// ======================================================================
__global__ __launch_bounds__(256)
void fourier_k(const float* __restrict__ spec, const float* __restrict__ fb,
               unsigned short* __restrict__ h0h)
{
    int j = blockIdx.x * 256 + threadIdx.x;   // grid.x=24 -> j<6144
    int m = blockIdx.y;
    if (j < NFREQ) {
        float mz  = spec[(size_t)m * 2];
        float ang = 6.2831853071795864769f * (mz * fb[j]);
        float s, c;
        sincosf(ang, &s, &c);
        size_t base = (size_t)m * KP0;
        h0h[base + j]         = bf16_hi(c);
        h0h[base + NFREQ + j] = bf16_hi(s);
    } else if (j + NFREQ < KP0) {             // zero pad cols 11994..12031
        h0h[(size_t)m * KP0 + j + NFREQ] = 0;
    }
}

// ======================================================================
// Peak embedding into x fp32 (cols DF_..DD_)
// ======================================================================
__global__ __launch_bounds__(64)
void peak_k(const float* __restrict__ spec, const float* __restrict__ pw,
            const float* __restrict__ pb, float* __restrict__ x)
{
    int m = blockIdx.x;
    int n = threadIdx.x;
    if (n >= DP_) return;
    float mz = spec[(size_t)m*2], it = spec[(size_t)m*2+1];
    float v = mz * pw[n*2] + it * pw[n*2+1] + pb[n];
    x[(size_t)m*DD_ + DF_ + n] = fmaxf(v, 0.f);
}

// ======================================================================
// fp32 weight [N][K] -> bf16 hi/lo planes [Npad][Kpad] (zero-padded)
// ======================================================================
__global__ __launch_bounds__(256)
void cvt_w(const float* __restrict__ W, unsigned short* __restrict__ hi,
           unsigned short* __restrict__ lo, int N, int K, int Npad, int Kpad)
{
    unsigned int total = (unsigned int)Npad * (unsigned int)Kpad;
    for (unsigned int idx = blockIdx.x*256u + threadIdx.x; idx < total;
         idx += gridDim.x * 256u) {
        float v;
        if (K == Kpad) {
            v = (idx < (unsigned int)N * (unsigned int)K) ? W[idx] : 0.f;
        } else {
            unsigned int n = idx / (unsigned int)Kpad, k = idx % (unsigned int)Kpad;
            v = (n < (unsigned int)N && k < (unsigned int)K) ? W[(size_t)n*K + k] : 0.f;
        }
        unsigned short h, l2; bf16_split(v, h, l2);
        hi[idx] = h; lo[idx] = l2;
    }
}

// ======================================================================
// Segmented-K split-precision MFMA GEMM (NT):
//   C[m][n] = sum_{seg} sum_k Aseg[m][k] * Bseg[n][k]
// segA={Ah,Al,Ah}, segB={Bh,Bh,Bl}: 3-term split product as ONE 2-plane
// bf16 GEMM stream. 128x128 tile, BK=64, 32 KB LDS, global_load_lds(16B)
// with pre-swizzled source + XOR-swizzled ds_read_b128 (0-conflict, R2).
// Segments explicitly unrolled (no runtime-indexed pointer array).
// XCD-aware flat-bid swizzle (all grids have nwg%8==0).
// ======================================================================
struct MgemmCtx {
    unsigned short* ldsA;
    unsigned short* ldsB;
    int tid, wr, wc, lrow, sidx, x7;
};

template<typename ACC>
__device__ __forceinline__ void mg_seg(const MgemmCtx& c,
                                       const unsigned short* gA,
                                       const unsigned short* gB,
                                       int K, ACC& acc)
{
    #pragma unroll 1
    for (int k0 = 0; k0 < K; k0 += 64) {
        __syncthreads();
        #pragma unroll
        for (int it = 0; it < 4; it++) {
            size_t go = (size_t)it * 32 * K + k0;
            int lo = it * 2048 + c.tid * 8;
            gl_lds16(gA + go, c.ldsA + lo);
            gl_lds16(gB + go, c.ldsB + lo);
        }
        __syncthreads();
        #pragma unroll
        for (int kk = 0; kk < 2; kk++) {
            const int sl = ((kk << 2) | c.sidx) ^ c.x7;
            short8_t bfr[4];
            #pragma unroll
            for (int ni = 0; ni < 4; ni++) {
                int rb = c.wc*64 + ni*16 + c.lrow;
                bfr[ni] = *(const short8_t*)((const char*)c.ldsB + rb*128 + sl*16);
            }
            #pragma unroll
            for (int mi = 0; mi < 4; mi++) {
                int ra = c.wr*64 + mi*16 + c.lrow;
                short8_t afr = *(const short8_t*)((const char*)c.ldsA + ra*128 + sl*16);
                #pragma unroll
                for (int ni = 0; ni < 4; ni++)
                    acc[mi][ni] = __builtin_amdgcn_mfma_f32_16x16x32_bf16(afr, bfr[ni], acc[mi][ni], 0, 0, 0);
            }
        }
    }
}

template<int NSEG, bool BIAS, bool RELU, bool RES, bool OUTPL>
__global__ __launch_bounds__(256)
void mgemmS(const unsigned short* __restrict__ A0, const unsigned short* __restrict__ A1,
            const unsigned short* __restrict__ A2,
            const unsigned short* __restrict__ B0, const unsigned short* __restrict__ B1,
            const unsigned short* __restrict__ B2,
            const float* __restrict__ bias,
            const float* __restrict__ resid, int ldres,
            float* __restrict__ Cf, unsigned short* __restrict__ Ch,
            unsigned short* __restrict__ Cl,
            int ldc, int N, int K)
{
    __shared__ __align__(16) unsigned short lds[2 * 8192];   // A tile + B tile
    const int tid = threadIdx.x;

    // XCD swizzle (nwg % 8 == 0 for all launches)
    const int nwg = gridDim.x * gridDim.y;
    const int bid = blockIdx.y * gridDim.x + blockIdx.x;
    const int sw  = (bid & 7) * (nwg >> 3) + (bid >> 3);
    const int bm = (sw / gridDim.x) * 128, bn = (sw % gridDim.x) * 128;

    // staging addresses (pre-swizzled source slot)
    const int r0 = tid >> 3;                  // 0..31 (row mod 32 of tile)
    const int ss = (tid & 7) ^ (r0 & 7);      // source 16B slot (involution)
    const size_t aoff = (size_t)(bm + r0) * K + ss * 8;
    const size_t boff = (size_t)(bn + r0) * K + ss * 8;

    MgemmCtx c;
    c.ldsA = lds; c.ldsB = lds + 8192;
    c.tid = tid;
    const int l = tid & 63, wid = tid >> 6;
    c.wr = wid >> 1; c.wc = wid & 1;          // wave -> 64x64 quadrant
    c.lrow = l & 15; c.sidx = l >> 4;
    c.x7 = c.lrow & 7;                        // swizzle key (row&7)

    f32x4 acc[4][4];
    #pragma unroll
    for (int i = 0; i < 4; i++)
        #pragma unroll
        for (int j = 0; j < 4; j++) acc[i][j] = (f32x4){0.f,0.f,0.f,0.f};

    mg_seg(c, A0 + aoff, B0 + boff, K, acc);
    if constexpr (NSEG >= 2) mg_seg(c, A1 + aoff, B1 + boff, K, acc);
    if constexpr (NSEG >= 3) mg_seg(c, A2 + aoff, B2 + boff, K, acc);

    // epilogue: C/D layout col=lane&15, row=(lane>>4)*4+q
    #pragma unroll
    for (int mi = 0; mi < 4; mi++) {
        #pragma unroll
        for (int ni = 0; ni < 4; ni++) {
            int n = bn + c.wc*64 + ni*16 + c.lrow;
            if (n < N) {
                #pragma unroll
                for (int q = 0; q < 4; q++) {
                    int m = bm + c.wr*64 + mi*16 + (c.sidx<<2) + q;
                    float v = acc[mi][ni][q];
                    if constexpr (BIAS) v += bias[n];
                    if constexpr (RES)  v += resid[(size_t)m*ldres + n];
                    if constexpr (RELU) v = fmaxf(v, 0.f);
                    if constexpr (OUTPL) {
                        unsigned short h, l2; bf16_split(v, h, l2);
                        Ch[(size_t)m*ldc + n] = h;
                        Cl[(size_t)m*ldc + n] = l2;
                    } else {
                        Cf[(size_t)m*ldc + n] = v;
                    }
                }
            }
        }
    }
}

// ======================================================================
// LayerNorm helpers
// ======================================================================
__device__ __forceinline__ float block_sum(float v, float* red, int tid)
{
    #pragma unroll
    for (int o = 32; o >= 1; o >>= 1) v += __shfl_xor(v, o, 64);
    if ((tid & 63) == 0) red[tid >> 6] = v;
    __syncthreads();
    float r = red[0] + red[1] + red[2] + red[3];
    __syncthreads();
    return r;
}

__global__ __launch_bounds__(256)
void ln_k(const float* __restrict__ x, const float* __restrict__ g,
          const float* __restrict__ bta, float* __restrict__ y)
{
    __shared__ float red[4];
    int m = blockIdx.x, tid = threadIdx.x;
    const float* xr = x + (size_t)m * DD_;
    float4 v = *(const float4*)&xr[tid*4];
    float mean = block_sum(v.x+v.y+v.z+v.w, red, tid) * (1.f/1024.f);
    float d0 = v.x-mean, d1 = v.y-mean, d2 = v.z-mean, d3 = v.w-mean;
    float var = block_sum(d0*d0+d1*d1+d2*d2+d3*d3, red, tid) * (1.f/1024.f);
    float inv = 1.0f / sqrtf(var + 1e-5f);
    float4 gg = *(const float4*)&g[tid*4];
    float4 bb = *(const float4*)&bta[tid*4];
    float4 o;
    o.x = d0*inv*gg.x + bb.x;  o.y = d1*inv*gg.y + bb.y;
    o.z = d2*inv*gg.z + bb.z;  o.w = d3*inv*gg.w + bb.w;
    *(float4*)&y[(size_t)m*DD_ + tid*4] = o;
}

__global__ __launch_bounds__(256)
void ln_planes(const float* __restrict__ x, const float* __restrict__ g,
               const float* __restrict__ bta,
               unsigned short* __restrict__ yh, unsigned short* __restrict__ yl)
{
    __shared__ float red[4];
    int m = blockIdx.x, tid = threadIdx.x;
    const float* xr = x + (size_t)m * DD_;
    float4 v = *(const float4*)&xr[tid*4];
    float mean = block_sum(v.x+v.y+v.z+v.w, red, tid) * (1.f/1024.f);
    float d0 = v.x-mean, d1 = v.y-mean, d2 = v.z-mean, d3 = v.w-mean;
    float var = block_sum(d0*d0+d1*d1+d2*d2+d3*d3, red, tid) * (1.f/1024.f);
    float inv = 1.0f / sqrtf(var + 1e-5f);
    float4 gg = *(const float4*)&g[tid*4];
    float4 bb = *(const float4*)&bta[tid*4];
    float o0 = d0*inv*gg.x + bb.x, o1 = d1*inv*gg.y + bb.y;
    float o2 = d2*inv*gg.z + bb.z, o3 = d3*inv*gg.w + bb.w;
    size_t base = (size_t)m*DD_ + tid*4;
    unsigned short h, l2;
    bf16_split(o0, h, l2); yh[base+0] = h; yl[base+0] = l2;
    bf16_split(o1, h, l2); yh[base+1] = h; yl[base+1] = l2;
    bf16_split(o2, h, l2); yh[base+2] = h; yl[base+2] = l2;
    bf16_split(o3, h, l2); yh[base+3] = h; yl[base+3] = l2;
}

// ======================================================================
// Attention (fp32, unchanged)
// ======================================================================
__global__ __launch_bounds__(256)
void attn_scores(const float* __restrict__ qkv, const float* __restrict__ spec,
                 float* __restrict__ sout)
{
    __shared__ float Qs[HDIM][68];
    __shared__ float Ks[HDIM][68];
    const int tid = threadIdx.x;
    const int bh = blockIdx.z, b = bh >> 3, h = bh & 7;
    const int i0 = blockIdx.y * 64, j0 = blockIdx.x * 64;
    const int lr = tid >> 2, ld0 = (tid & 3) * 32;
    {
        const float* qp = qkv + (size_t)(b*NSEQ + i0 + lr)*(3*DD_) + h*HDIM + ld0;
        const float* kp = qkv + (size_t)(b*NSEQ + j0 + lr)*(3*DD_) + DD_ + h*HDIM + ld0;
        #pragma unroll
        for (int c = 0; c < 32; c += 4) {
            float4 qv = *(const float4*)(qp + c);
            float4 kv = *(const float4*)(kp + c);
            Qs[ld0+c+0][lr]=qv.x; Qs[ld0+c+1][lr]=qv.y; Qs[ld0+c+2][lr]=qv.z; Qs[ld0+c+3][lr]=qv.w;
            Ks[ld0+c+0][lr]=kv.x; Ks[ld0+c+1][lr]=kv.y; Ks[ld0+c+2][lr]=kv.z; Ks[ld0+c+3][lr]=kv.w;
        }
    }
    __syncthreads();
    const int tx = tid & 15, ty = tid >> 4;
    float acc[4][4] = {};
    #pragma unroll 4
    for (int d = 0; d < HDIM; d++) {
        float a4[4], b4[4];
        *(float4*)a4 = *(const float4*)&Qs[d][ty*4];
        *(float4*)b4 = *(const float4*)&Ks[d][tx*4];
        #pragma unroll
        for (int i2 = 0; i2 < 4; i2++)
            #pragma unroll
            for (int j2 = 0; j2 < 4; j2++) acc[i2][j2] += a4[i2] * b4[j2];
    }
    const float scale = 0.08838834764831845f;   // 128^-0.5
    float mzi[4], mzj[4], itj[4];
    #pragma unroll
    for (int i2 = 0; i2 < 4; i2++) mzi[i2] = spec[(size_t)(b*NSEQ + i0 + ty*4 + i2)*2];
    #pragma unroll
    for (int j2 = 0; j2 < 4; j2++) {
        size_t jj = (size_t)(b*NSEQ + j0 + tx*4 + j2)*2;
        mzj[j2] = spec[jj]; itj[j2] = spec[jj+1];
    }
    float* srow = sout + ((size_t)bh*NSEQ + i0)*NSEQ + j0;
    #pragma unroll
    for (int i2 = 0; i2 < 4; i2++)
        #pragma unroll
        for (int j2 = 0; j2 < 4; j2++) {
            float v = acc[i2][j2]*scale + (mzi[i2] - mzj[j2]);
            if (itj[j2] == 0.f) v = -1000000000.0f;
            srow[(size_t)(ty*4+i2)*NSEQ + tx*4 + j2] = v;
        }
}

__global__ __launch_bounds__(256)
void softmax_k(float* __restrict__ s)
{
    int row  = blockIdx.x*4 + (threadIdx.x >> 6);
    int lane = threadIdx.x & 63;
    float* sr = s + (size_t)row * NSEQ;
    float v0 = sr[lane], v1 = sr[lane+64], v2 = sr[lane+128], v3 = sr[lane+192];
    float mx = fmaxf(fmaxf(v0,v1), fmaxf(v2,v3));
    #pragma unroll
    for (int o = 32; o >= 1; o >>= 1) mx = fmaxf(mx, __shfl_xor(mx, o, 64));
    float e0 = expf(v0-mx), e1 = expf(v1-mx), e2 = expf(v2-mx), e3 = expf(v3-mx);
    float sm = e0+e1+e2+e3;
    #pragma unroll
    for (int o = 32; o >= 1; o >>= 1) sm += __shfl_xor(sm, o, 64);
    float r = 1.0f / sm;
    sr[lane] = e0*r; sr[lane+64] = e1*r; sr[lane+128] = e2*r; sr[lane+192] = e3*r;
}

// PV -> bf16 hi/lo planes [4096][1024]
__global__ __launch_bounds__(256)
void attn_pv(const float* __restrict__ a, const float* __restrict__ qkv,
             unsigned short* __restrict__ oh, unsigned short* __restrict__ ol)
{
    __shared__ float As[32][NSEQ+1];
    const int tid = threadIdx.x;
    const int bh = blockIdx.y, b = bh >> 3, h = bh & 7;
    const int i0 = blockIdx.x * 32;
    {
        const int lr = tid >> 3, lc0 = (tid & 7) * 32;
        const float* ag = a + ((size_t)bh*NSEQ + i0 + lr)*NSEQ + lc0;
        #pragma unroll
        for (int c = 0; c < 32; c += 4) {
            float4 v = *(const float4*)(ag + c);
            As[lr][lc0+c+0]=v.x; As[lr][lc0+c+1]=v.y; As[lr][lc0+c+2]=v.z; As[lr][lc0+c+3]=v.w;
        }
    }
    __syncthreads();
    const int ii = tid >> 3, d0 = (tid & 7) * 16;
    const float* vbase = qkv + (size_t)b*NSEQ*3*DD_ + 2*DD_ + h*HDIM + d0;
    float acc[16] = {};
    for (int j = 0; j < NSEQ; j++) {
        float aval = As[ii][j];
        const float* vr = vbase + (size_t)j*3*DD_;
        float4 x0 = *(const float4*)(vr);
        float4 x1 = *(const float4*)(vr+4);
        float4 x2 = *(const float4*)(vr+8);
        float4 x3 = *(const float4*)(vr+12);
        acc[0]+=aval*x0.x; acc[1]+=aval*x0.y; acc[2]+=aval*x0.z; acc[3] +=aval*x0.w;
        acc[4]+=aval*x1.x; acc[5]+=aval*x1.y; acc[6] +=aval*x1.z; acc[7] +=aval*x1.w;
        acc[8]+=aval*x2.x; acc[9]+=aval*x2.y; acc[10]+=aval*x2.z; acc[11]+=aval*x2.w;
        acc[12]+=aval*x3.x; acc[13]+=aval*x3.y; acc[14]+=aval*x3.z; acc[15]+=aval*x3.w;
    }
    size_t base = (size_t)(b*NSEQ + i0 + ii)*DD_ + h*HDIM + d0;
    #pragma unroll
    for (int t = 0; t < 16; t++) {
        unsigned short h2, l2; bf16_split(acc[t], h2, l2);
        oh[base + t] = h2; ol[base + t] = l2;
    }
}

// ======================================================================
// Launch. ws layout identical to R2 (313 MB).
// ======================================================================
extern "C" void kernel_launch(void* const* d_in, const int* in_sizes, int n_in,
                              void* d_out, int out_size, void* d_ws, size_t ws_size,
                              hipStream_t stream)
{
    const float* spec = (const float*)d_in[0];
    const float* fb   = (const float*)d_in[1];
    const float* pw   = (const float*)d_in[2];
    const float* pb   = (const float*)d_in[3];
    const float* fw[5]    = {(const float*)d_in[4], (const float*)d_in[6],
                             (const float*)d_in[8], (const float*)d_in[10],
                             (const float*)d_in[12]};
    const float* fbias[5] = {(const float*)d_in[5], (const float*)d_in[7],
                             (const float*)d_in[9], (const float*)d_in[11],
                             (const float*)d_in[13]};
    const float* w_qkvo = (const float*)d_in[14];
    const float* ffn_w1 = (const float*)d_in[15];
    const float* ffn_w2 = (const float*)d_in[16];
    const float* ln1g = (const float*)d_in[17], *ln1b = (const float*)d_in[18];
    const float* ln2g = (const float*)d_in[19], *ln2b = (const float*)d_in[20];
    const float* lnfg = (const float*)d_in[21], *lnfb = (const float*)d_in[22];
    float* out = (float*)d_out;

    unsigned short* p = (unsigned short*)d_ws;
    unsigned short* h0h = p;                 p += 49283072;
    unsigned short* Hph = h0h;                               // alias (h0h dead)
    unsigned short* Hpl = h0h + 16777216;
    unsigned short* fw0h = p;                p += 6160384;
    unsigned short* fw0l = p;                p += 6160384;
    unsigned short* fwkh[3], *fwkl[3];
    for (int i = 0; i < 3; i++) { fwkh[i] = p; p += 262144; fwkl[i] = p; p += 262144; }
    unsigned short* fw4h = p;                p += 524288;
    unsigned short* fw4l = p;                p += 524288;
    unsigned short* P1h = p;                 p += 4194304;
    unsigned short* P1l = p;                 p += 4194304;
    unsigned short* P2h = p;                 p += 4194304;
    unsigned short* P2l = p;                 p += 4194304;
    unsigned short* wqh = p;                 p += 4194304;
    unsigned short* wql = p;                 p += 4194304;
    unsigned short* wf1h = p;                p += 4194304;
    unsigned short* wf1l = p;                p += 4194304;
    unsigned short* wf2h = p;                p += 4194304;
    unsigned short* wf2l = p;                p += 4194304;
    float* fx   = (float*)p;
    float* x    = fx;                        fx += 4194304;
    float* qkv  = fx;                        fx += 12582912;
    float* sbuf = fx;                        fx += 8388608;

    // ---- weight planes (once per call) ----
    cvt_w<<<8192, 256, 0, stream>>>(fw[0], fw0h, fw0l, 512, 11994, 512, KP0);
    for (int i = 0; i < 3; i++)
        cvt_w<<<1024, 256, 0, stream>>>(fw[1+i], fwkh[i], fwkl[i], 512, 512, 512, 512);
    cvt_w<<<2048, 256, 0, stream>>>(fw[4], fw4h, fw4l, 980, 512, 1024, 512);

    // ---- Fourier features + MLP (segmented-K MFMA) ----
    fourier_k<<<dim3(24, MTOK), 256, 0, stream>>>(spec, fb, h0h);
    mgemmS<2,true,true,false,true><<<dim3(4,32),256,0,stream>>>(
        h0h, h0h, nullptr, fw0h, fw0l, nullptr, fbias[0], nullptr,0,
        nullptr, P1h, P1l, 512, 512, KP0);
    mgemmS<3,true,true,false,true><<<dim3(4,32),256,0,stream>>>(
        P1h, P1l, P1h, fwkh[0], fwkh[0], fwkl[0], fbias[1], nullptr,0,
        nullptr, P2h, P2l, 512, 512, 512);
    mgemmS<3,true,true,false,true><<<dim3(4,32),256,0,stream>>>(
        P2h, P2l, P2h, fwkh[1], fwkh[1], fwkl[1], fbias[2], nullptr,0,
        nullptr, P1h, P1l, 512, 512, 512);
    mgemmS<3,true,true,false,true><<<dim3(4,32),256,0,stream>>>(
        P1h, P1l, P1h, fwkh[2], fwkh[2], fwkl[2], fbias[3], nullptr,0,
        nullptr, P2h, P2l, 512, 512, 512);
    mgemmS<3,true,true,false,false><<<dim3(8,32),256,0,stream>>>(
        P2h, P2l, P2h, fw4h, fw4h, fw4l, fbias[4], nullptr,0,
        x, nullptr, nullptr, DD_, DF_, 512);
    peak_k<<<dim3(MTOK), 64, 0, stream>>>(spec, pw, pb, x);

    // ---- Transformer layers ----
    for (int i = 0; i < L_; i++) {
        const float* Wq = w_qkvo + (size_t)i*4*DD_*DD_;
        cvt_w<<<16384,256,0,stream>>>(Wq, wqh, wql, 4096, 1024, 4096, 1024);
        ln_planes<<<MTOK,256,0,stream>>>(x, ln1g + i*DD_, ln1b + i*DD_, P1h, P1l);
        mgemmS<3,false,false,false,false><<<dim3(24,32),256,0,stream>>>(
            P1h, P1l, P1h, wqh, wqh, wql, nullptr, nullptr,0,
            qkv, nullptr, nullptr, 3*DD_, 3*DD_, DD_);
        attn_scores<<<dim3(4,4,B_*H_),256,0,stream>>>(qkv, spec, sbuf);
        softmax_k<<<dim3(B_*H_*NSEQ/4),256,0,stream>>>(sbuf);
        attn_pv<<<dim3(8,B_*H_),256,0,stream>>>(sbuf, qkv, P2h, P2l);
        mgemmS<3,false,false,true,false><<<dim3(8,32),256,0,stream>>>(
            P2h, P2l, P2h, wqh + (size_t)3072*1024, wqh + (size_t)3072*1024,
            wql + (size_t)3072*1024, nullptr, x, DD_,
            x, nullptr, nullptr, DD_, DD_, DD_);
        cvt_w<<<16384,256,0,stream>>>(ffn_w1 + (size_t)i*FF_*DD_, wf1h, wf1l, 4096, 1024, 4096, 1024);
        ln_planes<<<MTOK,256,0,stream>>>(x, ln2g + i*DD_, ln2b + i*DD_, P1h, P1l);
        mgemmS<3,false,true,false,true><<<dim3(32,32),256,0,stream>>>(
            P1h, P1l, P1h, wf1h, wf1h, wf1l, nullptr, nullptr,0,
            nullptr, Hph, Hpl, FF_, FF_, DD_);
        cvt_w<<<16384,256,0,stream>>>(ffn_w2 + (size_t)i*DD_*FF_, wf2h, wf2l, 1024, 4096, 1024, 4096);
        mgemmS<3,false,false,true,false><<<dim3(8,32),256,0,stream>>>(
            Hph, Hpl, Hph, wf2h, wf2h, wf2l, nullptr, x, DD_,
            x, nullptr, nullptr, DD_, DD_, FF_);
    }
    ln_k<<<MTOK,256,0,stream>>>(x, lnfg, lnfb, out);
}